// Round 16
// baseline (82.691 us; speedup 1.0000x reference)
//
#include <hip/hip_runtime.h>
#include <hip/hip_bf16.h>

#define LOG2E 1.4426950408889634f

typedef __attribute__((ext_vector_type(8))) short short8;
typedef __attribute__((ext_vector_type(8))) __bf16 bf16x8;
typedef __attribute__((ext_vector_type(4))) float f32x4;

__device__ __forceinline__ unsigned short f2b(float f){
  unsigned int u = __builtin_bit_cast(unsigned int, f);
  u += 0x7fffu + ((u >> 16) & 1u);
  return (unsigned short)(u >> 16);
}

__device__ __forceinline__ unsigned int cvtpk(float lo, float hi){
  unsigned int r;
  asm("v_cvt_pk_bf16_f32 %0, %1, %2" : "=v"(r) : "v"(lo), "v"(hi));
  return r;
}

__device__ __forceinline__ void gload16(const void* g, void* l){
  __builtin_amdgcn_global_load_lds(
      (const __attribute__((address_space(1))) unsigned int*)g,
      (__attribute__((address_space(3))) unsigned int*)l, 16, 0, 0);
}

// ---------------- merged prep kernel: x->bf16, Wqkv^T, Wproj^T ----------------
__global__ __launch_bounds__(256) void prep_kernel(
    const float* __restrict__ x, const float* __restrict__ Wqkv, const float* __restrict__ Wproj,
    unsigned short* __restrict__ xb, unsigned short* __restrict__ wqkvT, unsigned short* __restrict__ wprojT){
  __shared__ unsigned short T[64][72];
  const int bid = blockIdx.x, tid = threadIdx.x;
  if (bid < 2048){
    size_t i = ((size_t)bid * 256 + tid) * 8;
    float4 a = *(const float4*)(x + i);
    float4 b = *(const float4*)(x + i + 4);
    short8 s;
    s[0]=(short)f2b(a.x); s[1]=(short)f2b(a.y); s[2]=(short)f2b(a.z); s[3]=(short)f2b(a.w);
    s[4]=(short)f2b(b.x); s[5]=(short)f2b(b.y); s[6]=(short)f2b(b.z); s[7]=(short)f2b(b.w);
    *(short8*)(xb + i) = s;
    return;
  }
  const float* in; unsigned short* out; int R, C, bx, by;
  if (bid < 2240){ int t = bid - 2048; bx = t % 24; by = t / 24; in = Wqkv; out = wqkvT; R = 512; C = 1536; }
  else           { int t = bid - 2240; bx = t % 8;  by = t / 8;  in = Wproj; out = wprojT; R = 512; C = 512; }
  const int r0 = by * 64, c0 = bx * 64;
  {
    const int i = tid >> 2, jg = (tid & 3) * 16;
    const float* src = in + (size_t)(r0 + i) * C + c0 + jg;
    #pragma unroll
    for (int e = 0; e < 16; e += 4){
      float4 v = *(const float4*)(src + e);
      T[i][jg + e + 0] = f2b(v.x);
      T[i][jg + e + 1] = f2b(v.y);
      T[i][jg + e + 2] = f2b(v.z);
      T[i][jg + e + 3] = f2b(v.w);
    }
  }
  __syncthreads();
  {
    const int j = tid >> 2, ig = (tid & 3) * 16;
    short8 w0, w1;
    #pragma unroll
    for (int e = 0; e < 8; e++) w0[e] = (short)T[ig + e][j];
    #pragma unroll
    for (int e = 0; e < 8; e++) w1[e] = (short)T[ig + 8 + e][j];
    unsigned short* dst = out + (size_t)(c0 + j) * R + r0 + ig;
    *(short8*)dst = w0;
    *(short8*)(dst + 8) = w1;
  }
}

// ---------------- QKV GEMM (BK=64, global_load_lds, XCD-swizzled, 3 blocks/CU) ----------------
__global__ __launch_bounds__(256,3) void gemm_qkv_kernel(
    const unsigned short* __restrict__ A,
    const unsigned short* __restrict__ Bt,
    const float* __restrict__ bias,
    unsigned short* __restrict__ Qb,
    unsigned short* __restrict__ Kb,
    unsigned short* __restrict__ VTb,
    float* __restrict__ Mq, float* __restrict__ Mk){
  __shared__ unsigned short As[128*64];
  __shared__ unsigned short Bs[128*64];
  const int tid = threadIdx.x, wid = tid >> 6, lane = tid & 63;
  const int wr = wid >> 1, wc = wid & 1;
  const int fr = lane & 15, fq = lane >> 4;
  const int fr7 = fr & 7;
  const int orig = blockIdx.x;
  const int xcd = orig & 7, idx = orig >> 3;
  const int bm = (xcd + 8*(idx/12)) * 128;
  const int bn = (idx % 12) * 128;
  f32x4 acc[4][4];
  #pragma unroll
  for (int m=0;m<4;m++)
    #pragma unroll
    for (int n=0;n<4;n++) acc[m][n] = (f32x4){0.f,0.f,0.f,0.f};

  for (int k0 = 0; k0 < 512; k0 += 64){
    __syncthreads();
    #pragma unroll
    for (int it=0; it<4; it++){
      const int s = it*256 + tid;
      const int row = s >> 3, c = s & 7;
      const int sc = c ^ (row & 7);
      void* al = (void*)(As + (it*256 + wid*64)*8);
      void* bl = (void*)(Bs + (it*256 + wid*64)*8);
      gload16(A  + (size_t)(bm + row)*512 + k0 + sc*8, al);
      gload16(Bt + (size_t)(bn + row)*512 + k0 + sc*8, bl);
    }
    __syncthreads();
    bf16x8 af[4][2], bfv[4][2];
    #pragma unroll
    for (int m=0;m<4;m++)
      #pragma unroll
      for (int kk=0;kk<2;kk++)
        af[m][kk]  = *(const bf16x8*)&As[(wr*64 + m*16 + fr)*64 + (((kk*4+fq)^fr7)*8)];
    #pragma unroll
    for (int n=0;n<4;n++)
      #pragma unroll
      for (int kk=0;kk<2;kk++)
        bfv[n][kk] = *(const bf16x8*)&Bs[(wc*64 + n*16 + fr)*64 + (((kk*4+fq)^fr7)*8)];
    #pragma unroll
    for (int kk=0;kk<2;kk++)
      #pragma unroll
      for (int m=0;m<4;m++)
        #pragma unroll
        for (int n=0;n<4;n++)
          acc[m][n] = __builtin_amdgcn_mfma_f32_16x16x32_bf16(af[m][kk], bfv[n][kk], acc[m][n], 0,0,0);
  }

  const float SCQ = 0.125f * LOG2E;
  const int colbase = bn + wc*64;
  const int which = colbase >> 9;
  float ss[4][4];
  #pragma unroll
  for (int m=0;m<4;m++)
    #pragma unroll
    for (int g=0;g<4;g++) ss[m][g] = 0.f;

  #pragma unroll
  for (int m=0;m<4;m++){
    const int row0 = bm + wr*64 + m*16 + fq*4;
    const int b_ = row0 >> 11, t_ = row0 & 2047;
    #pragma unroll
    for (int n=0;n<4;n++){
      const int col = colbase + n*16 + fr;
      const int c = col & 511, hh = c >> 6, dd = c & 63;
      const float bv = bias[col];
      if (which == 0){
        #pragma unroll
        for (int g=0; g<4; g++){
          const float v = (acc[m][n][g] + bv) * SCQ;
          ss[m][g] = fmaf(v, v, ss[m][g]);
          Qb[((size_t)(b_*8 + hh)*2048 + t_ + g)*64 + dd] = f2b(v);
        }
      } else if (which == 1){
        #pragma unroll
        for (int g=0; g<4; g++){
          const float v = acc[m][n][g] + bv;
          ss[m][g] = fmaf(v, v, ss[m][g]);
          Kb[((size_t)(b_*8 + hh)*2048 + t_ + g)*64 + dd] = f2b(v);
        }
      } else {
        uint2 pk;
        pk.x = cvtpk(acc[m][n][0] + bv, acc[m][n][1] + bv);
        pk.y = cvtpk(acc[m][n][2] + bv, acc[m][n][3] + bv);
        *(uint2*)&VTb[((size_t)(b_*8 + hh)*64 + dd)*2048 + t_] = pk;
      }
    }
  }

  if (which <= 1){
    #pragma unroll
    for (int m=0;m<4;m++)
      #pragma unroll
      for (int g=0;g<4;g++){
        float s = ss[m][g];
        s += __shfl_xor(s, 1); s += __shfl_xor(s, 2);
        s += __shfl_xor(s, 4); s += __shfl_xor(s, 8);
        ss[m][g] = s;
      }
    float mx = 0.f;
    #pragma unroll
    for (int m=0;m<4;m++)
      #pragma unroll
      for (int g=0;g<4;g++) mx = fmaxf(mx, ss[m][g]);
    mx = fmaxf(mx, __shfl_xor(mx, 16));
    mx = fmaxf(mx, __shfl_xor(mx, 32));
    if (lane == 0){
      const int rowbase = bm + wr*64;
      const int b_ = rowbase >> 11, qc_ = (rowbase >> 6) & 31;
      const int h_ = (colbase >> 6) & 7;
      float* M = which ? Mk : Mq;
      M[(b_*8 + h_)*32 + qc_] = sqrtf(mx) * 1.01f;
    }
  }
}

// ---------------- windowed flash attention: 8 waves, 128 q-rows/block ----------------
// Static-shift softmax; per-wave chunk qcW; KV tile staged once per 128 rows.
__global__ __launch_bounds__(512,4) void attn_kernel(
    const unsigned short* __restrict__ Q,
    const unsigned short* __restrict__ K,
    const unsigned short* __restrict__ VT,
    const float* __restrict__ alib,
    const float* __restrict__ Mqa,
    const float* __restrict__ Mka,
    unsigned short* __restrict__ Y){
  __shared__ unsigned short Ks[2][64*64];
  __shared__ unsigned short Vs[2][64*64];
  __shared__ unsigned short Ps[8][16][72];
  __shared__ float MkS[32];
  __shared__ float wred[8];
  __shared__ int lst[32];
  __shared__ int nsh;
  const int tid = threadIdx.x, wid = tid >> 6, lane = tid & 63;
  const int fr = lane & 15, fq = lane >> 4;
  const int fr7 = fr & 7;
  // id -> (h, b, c): XCD colocation of same-(b,h) pairs; h-major for LPT
  const int id = blockIdx.x;
  const int h = id >> 6;
  const int r_ = id & 63, xcd = r_ & 7, s_ = r_ >> 3;
  const int b = s_ >> 1;
  const int c = ((xcd + b) & 7)*2 + (s_ & 1);     // 0..15
  const int bh = b*8 + h;
  const int tA = 2*c, tB = 2*c + 1;
  const int q0 = c*128 + wid*16;
  const int qcW = q0 >> 6;                        // wave's chunk (tA or tB)
  const unsigned short* Qp = Q  + (size_t)bh * 131072;
  const unsigned short* Kp = K  + (size_t)bh * 131072;
  const unsigned short* Vp = VT + (size_t)bh * 131072;
  const float nmh2 = alib[(size_t)h * 4194304 + 1] * LOG2E;
  const float MqW = Mqa[bh*32 + qcW];
  if (tid < 32) MkS[tid] = Mka[bh*32 + tid];

  // block-uniform maxMk via per-wave reduce of direct global reads
  float vmk = Mka[bh*32 + (lane & 31)];
  #pragma unroll
  for (int d=1; d<32; d<<=1) vmk = fmaxf(vmk, __shfl_xor(vmk, d));
  const float msta = MqW * vmk;       // per-wave upper bound on log2-domain score

  bf16x8 qf[2];
  #pragma unroll
  for (int kk=0;kk<2;kk++)
    qf[kk] = *(const bf16x8*)(Qp + (size_t)(q0 + fr)*64 + kk*32 + fq*8);

  bf16x8 ones;
  #pragma unroll
  for (int e=0;e<8;e++) ones[e] = __builtin_bit_cast(__bf16, (unsigned short)0x3F80);

  f32x4 o[4], osum;
  #pragma unroll
  for (int ni=0;ni<4;ni++) o[ni] = (f32x4){0.f,0.f,0.f,0.f};
  osum = (f32x4){0.f,0.f,0.f,0.f};
  float rowmax = -1e30f;
  const float qi = (float)(q0 + fr);
  const float qb = nmh2 * qi;
  f32x4 ka[4];
  #pragma unroll
  for (int ni=0;ni<4;ni++)
    #pragma unroll
    for (int g=0;g<4;g++) ka[ni][g] = nmh2 * (float)(ni*16 + fq*4 + g);

  // 512 threads: 1 K-load + 1 V-load per thread per tile
  auto stage = [&](int kt, int buf){
    const int kb = kt * 64;
    const int row = tid >> 3, cc = tid & 7;
    const int sc = cc ^ (row & 7);
    gload16(Kp + (size_t)(kb + row)*64 + sc*8, (void*)(Ks[buf] + wid*64*8));
    gload16(Vp + (size_t)row*2048 + kb + sc*8, (void*)(Vs[buf] + wid*64*8));
  };

  auto computeT = [&](int kt, int buf, bool track){
    const int kb = kt * 64;
    const unsigned short* KsB = Ks[buf];
    const unsigned short* VsB = Vs[buf];
    bf16x8 kf[4][2], vf[4][2];
    #pragma unroll
    for (int ni=0;ni<4;ni++)
      #pragma unroll
      for (int kk=0;kk<2;kk++){
        const int r = ni*16 + fr;
        const int sw = ((kk*4 + fq) ^ fr7) * 8;
        kf[ni][kk] = *(const bf16x8*)&KsB[r*64 + sw];
        vf[ni][kk] = *(const bf16x8*)&VsB[r*64 + sw];
      }

    f32x4 st[4];
    const f32x4 fz = {0.f,0.f,0.f,0.f};
    #pragma unroll
    for (int ni=0;ni<4;ni++){
      f32x4 t0 = __builtin_amdgcn_mfma_f32_16x16x32_bf16(kf[ni][0], qf[0], fz, 0,0,0);
      st[ni] = __builtin_amdgcn_mfma_f32_16x16x32_bf16(kf[ni][1], qf[1], t0, 0,0,0);
    }

    float cadd;
    if (kt == qcW){                        // wave-uniform diagonal
      const float base = qi - (float)(kb + fq*4);
      #pragma unroll
      for (int ni=0;ni<4;ni++)
        #pragma unroll
        for (int g=0;g<4;g++){
          const float d = fabsf(base - (float)(ni*16 + g));
          st[ni][g] = fmaf(nmh2, d, st[ni][g]);
        }
      cadd = 0.f;
    } else {
      const float s1 = (kt > qcW) ? 1.f : -1.f;
      #pragma unroll
      for (int ni=0;ni<4;ni++)
        #pragma unroll
        for (int g=0;g<4;g++)
          st[ni][g] = fmaf(s1, ka[ni][g], st[ni][g]);
      cadd = s1 * (nmh2 * (float)kb - qb);
    }

    if (track){                            // prologue tiles: row max for thresholds
      float m0 = fmaxf(fmaxf(st[0][0], st[0][1]), fmaxf(st[0][2], st[0][3]));
      float m1 = fmaxf(fmaxf(st[1][0], st[1][1]), fmaxf(st[1][2], st[1][3]));
      float m2 = fmaxf(fmaxf(st[2][0], st[2][1]), fmaxf(st[2][2], st[2][3]));
      float m3 = fmaxf(fmaxf(st[3][0], st[3][1]), fmaxf(st[3][2], st[3][3]));
      float tm = fmaxf(fmaxf(m0, m1), fmaxf(m2, m3));
      tm = fmaxf(tm, __shfl_xor(tm, 16));
      tm = fmaxf(tm, __shfl_xor(tm, 32));
      rowmax = fmaxf(rowmax, tm + cadd);
    }

    const float mexp = msta - cadd;
    #pragma unroll
    for (int ni=0;ni<4;ni++)
      #pragma unroll
      for (int g=0;g<4;g++)
        st[ni][g] = exp2f(st[ni][g] - mexp);

    #pragma unroll
    for (int ni=0;ni<4;ni++){
      uint2 pk;
      pk.x = cvtpk(st[ni][0], st[ni][1]);
      pk.y = cvtpk(st[ni][2], st[ni][3]);
      *(uint2*)&Ps[wid][fr][ni*16 + fq*4] = pk;
    }

    bf16x8 pf[2];
    #pragma unroll
    for (int kk=0;kk<2;kk++)
      pf[kk] = *(const bf16x8*)&Ps[wid][fr][kk*32 + fq*8];
    #pragma unroll
    for (int ni=0;ni<4;ni++){
      o[ni] = __builtin_amdgcn_mfma_f32_16x16x32_bf16(pf[0], vf[ni][0], o[ni], 0,0,0);
      o[ni] = __builtin_amdgcn_mfma_f32_16x16x32_bf16(pf[1], vf[ni][1], o[ni], 0,0,0);
    }
    osum = __builtin_amdgcn_mfma_f32_16x16x32_bf16(pf[0], ones, osum, 0,0,0);
    osum = __builtin_amdgcn_mfma_f32_16x16x32_bf16(pf[1], ones, osum, 0,0,0);
  };

  // ---- prologue: both diagonal tiles; all waves compute both ----
  const int f0 = (tA - 1 >= 0) ? tA - 1 : tB + 1;     // always exists
  stage(tA, 0);
  stage(tB, 1);
  asm volatile("s_waitcnt vmcnt(2)" ::: "memory");
  __builtin_amdgcn_sched_barrier(0);
  __builtin_amdgcn_s_barrier();
  computeT(tA, 0, true);
  asm volatile("s_waitcnt vmcnt(0)" ::: "memory");
  __builtin_amdgcn_sched_barrier(0);
  __builtin_amdgcn_s_barrier();            // tB staged; all waves done with buf0
  stage(f0, 0);                            // prestage first ring tile
  computeT(tB, 1, true);

  // ---- thresholds (per-wave + block) ----
  float wm = rowmax;
  #pragma unroll
  for (int d=1; d<16; d<<=1) wm = fminf(wm, __shfl_xor(wm, d));
  if (lane == 0) wred[wid] = wm;
  __syncthreads();
  float thresh = wred[0];
  #pragma unroll
  for (int w=1; w<8; w++) thresh = fminf(thresh, wred[w]);
  thresh -= 14.0f;
  const float threshW = wm - 14.0f;

  // ---- build tile list around the pair ----
  if (tid == 0){
    float maxMk = 0.f;
    #pragma unroll
    for (int t=0; t<32; t++) maxMk = fmaxf(maxMk, MkS[t]);
    const float MqA = Mqa[bh*32 + tA];
    const float MqB = Mqa[bh*32 + tB];
    const float Mqmax = fmaxf(MqA, MqB);
    int n = 0;
    if (tA - 1 >= 0 && tB + 1 < 32) lst[n++] = tB + 1;   // the other ring-1 tile
    for (int dt = 2; dt < 32; dt++){
      const float biasmax = nmh2 * (float)((dt - 1)*64 + 1);
      if (Mqmax * maxMk + biasmax < thresh) break;
      int kt = tB + dt;
      if (kt < 32 && MqB * MkS[kt] + biasmax >= thresh) lst[n++] = kt;
      kt = tA - dt;
      if (kt >= 0 && MqA * MkS[kt] + biasmax >= thresh) lst[n++] = kt;
    }
    nsh = n;
  }
  __syncthreads();
  const int nt = nsh + 1;      // tiles: f0 (in buf0), lst[0..nsh-1]

  // ---- pipelined loop: tile j lives in buffer j&1 ----
  for (int j = 0; j < nt; j++){
    const int kt = (j == 0) ? f0 : lst[j-1];
    asm volatile("s_waitcnt lgkmcnt(0)" ::: "memory");
    __builtin_amdgcn_sched_barrier(0);
    __builtin_amdgcn_s_barrier();                  // safe to overwrite buf (j+1)&1
    if (j + 1 < nt){
      stage(lst[j], (j+1)&1);
      asm volatile("s_waitcnt vmcnt(2)" ::: "memory");
    } else {
      asm volatile("s_waitcnt vmcnt(0)" ::: "memory");
    }
    __builtin_amdgcn_sched_barrier(0);
    __builtin_amdgcn_s_barrier();                  // tile j staged for all waves
    const int dminW = (kt*64 > q0 + 15) ? (kt*64 - (q0 + 15)) : (q0 - (kt*64 + 63));
    if (MqW * MkS[kt] + nmh2 * (float)dminW >= threshW)
      computeT(kt, j&1, false);
  }

  // ---- epilogue ----
  #pragma unroll
  for (int g=0;g<4;g++){
    const float iv = 1.0f / osum[g];
    const int t = q0 + fq*4 + g;
    #pragma unroll
    for (int ni=0;ni<4;ni++)
      Y[(size_t)(b*2048 + t)*512 + h*64 + ni*16 + fr] = f2b(o[ni][g] * iv);
  }
}

// ---------------- output projection GEMM (BK=64, global_load_lds, XCD-swizzled) ----------------
__global__ __launch_bounds__(256,2) void gemm_proj_kernel(
    const unsigned short* __restrict__ A,
    const unsigned short* __restrict__ Bt,
    const float* __restrict__ bias,
    float* __restrict__ out){
  __shared__ unsigned short As[128*64];
  __shared__ unsigned short Bs[128*64];
  const int tid = threadIdx.x, wid = tid >> 6, lane = tid & 63;
  const int wr = wid >> 1, wc = wid & 1;
  const int fr = lane & 15, fq = lane >> 4;
  const int fr7 = fr & 7;
  const int orig = blockIdx.x;
  const int xcd = orig & 7, idx = orig >> 3;
  const int bm = (xcd + 8*(idx >> 2)) * 128;
  const int bn = (idx & 3) * 128;
  f32x4 acc[4][4];
  #pragma unroll
  for (int m=0;m<4;m++)
    #pragma unroll
    for (int n=0;n<4;n++) acc[m][n] = (f32x4){0.f,0.f,0.f,0.f};

  for (int k0 = 0; k0 < 512; k0 += 64){
    __syncthreads();
    #pragma unroll
    for (int it=0; it<4; it++){
      const int s = it*256 + tid;
      const int row = s >> 3, c = s & 7;
      const int sc = c ^ (row & 7);
      void* al = (void*)(As + (it*256 + wid*64)*8);
      void* bl = (void*)(Bs + (it*256 + wid*64)*8);
      gload16(A  + (size_t)(bm + row)*512 + k0 + sc*8, al);
      gload16(Bt + (size_t)(bn + row)*512 + k0 + sc*8, bl);
    }
    __syncthreads();
    bf16x8 af[4][2], bfv[4][2];
    #pragma unroll
    for (int m=0;m<4;m++)
      #pragma unroll
      for (int kk=0;kk<2;kk++)
        af[m][kk]  = *(const bf16x8*)&As[(wr*64 + m*16 + fr)*64 + (((kk*4+fq)^fr7)*8)];
    #pragma unroll
    for (int n=0;n<4;n++)
      #pragma unroll
      for (int kk=0;kk<2;kk++)
        bfv[n][kk] = *(const bf16x8*)&Bs[(wc*64 + n*16 + fr)*64 + (((kk*4+fq)^fr7)*8)];
    #pragma unroll
    for (int kk=0;kk<2;kk++)
      #pragma unroll
      for (int m=0;m<4;m++)
        #pragma unroll
        for (int n=0;n<4;n++)
          acc[m][n] = __builtin_amdgcn_mfma_f32_16x16x32_bf16(af[m][kk], bfv[n][kk], acc[m][n], 0,0,0);
  }

  #pragma unroll
  for (int m=0;m<4;m++){
    const int row0 = bm + wr*64 + m*16 + fq*4;
    #pragma unroll
    for (int n=0;n<4;n++){
      const int col = bn + wc*64 + n*16 + fr;
      const float bv = bias[col];
      #pragma unroll
      for (int g=0; g<4; g++)
        out[(size_t)(row0 + g)*512 + col] = acc[m][n][g] + bv;
    }
  }
}

// ---------------- launch ----------------
extern "C" void kernel_launch(void* const* d_in, const int* in_sizes, int n_in,
                              void* d_out, int out_size, void* d_ws, size_t ws_size,
                              hipStream_t stream){
  const float* x     = (const float*)d_in[0];
  const float* Wqkv  = (const float*)d_in[1];
  const float* bqkv  = (const float*)d_in[2];
  const float* Wproj = (const float*)d_in[3];
  const float* bproj = (const float*)d_in[4];
  const float* alib  = (const float*)d_in[5];
  char* ws = (char*)d_ws;
  unsigned short* xb     = (unsigned short*)(ws);
  unsigned short* wqkvT  = (unsigned short*)(ws + 8388608);
  unsigned short* wprojT = (unsigned short*)(ws + 9961472);
  unsigned short* Qb     = (unsigned short*)(ws + 10485760);
  unsigned short* Kb     = (unsigned short*)(ws + 18874368);
  unsigned short* VTb    = (unsigned short*)(ws + 27262976);
  unsigned short* Yb     = (unsigned short*)(ws + 35651584);
  float* out = (float*)d_out;
  float* Mq = out + 4194304 - 2048;
  float* Mk = Mq + 1024;

  prep_kernel<<<2304, 256, 0, stream>>>(x, Wqkv, Wproj, xb, wqkvT, wprojT);
  gemm_qkv_kernel<<<768, 256, 0, stream>>>(xb, wqkvT, bqkv, Qb, Kb, VTb, Mq, Mk);
  attn_kernel<<<512, 512, 0, stream>>>(Qb, Kb, VTb, alib, Mq, Mk, Yb);
  gemm_proj_kernel<<<256, 256, 0, stream>>>(Yb, wprojT, bproj, out);
}

// Round 17
// 65.151 us; speedup vs baseline: 1.2692x; 1.2692x over previous
//
#include <hip/hip_runtime.h>
#include <hip/hip_bf16.h>

#define LOG2E 1.4426950408889634f

typedef __attribute__((ext_vector_type(8))) short short8;
typedef __attribute__((ext_vector_type(8))) __bf16 bf16x8;
typedef __attribute__((ext_vector_type(4))) float f32x4;

__device__ __forceinline__ unsigned short f2b(float f){
  unsigned int u = __builtin_bit_cast(unsigned int, f);
  u += 0x7fffu + ((u >> 16) & 1u);
  return (unsigned short)(u >> 16);
}

__device__ __forceinline__ unsigned int cvtpk(float lo, float hi){
  unsigned int r;
  asm("v_cvt_pk_bf16_f32 %0, %1, %2" : "=v"(r) : "v"(lo), "v"(hi));
  return r;
}

__device__ __forceinline__ void gload16(const void* g, void* l){
  __builtin_amdgcn_global_load_lds(
      (const __attribute__((address_space(1))) unsigned int*)g,
      (__attribute__((address_space(3))) unsigned int*)l, 16, 0, 0);
}

// ---------------- merged prep kernel: x->bf16, Wqkv^T, Wproj^T ----------------
__global__ __launch_bounds__(256) void prep_kernel(
    const float* __restrict__ x, const float* __restrict__ Wqkv, const float* __restrict__ Wproj,
    unsigned short* __restrict__ xb, unsigned short* __restrict__ wqkvT, unsigned short* __restrict__ wprojT){
  __shared__ unsigned short T[64][72];
  const int bid = blockIdx.x, tid = threadIdx.x;
  if (bid < 2048){
    size_t i = ((size_t)bid * 256 + tid) * 8;
    float4 a = *(const float4*)(x + i);
    float4 b = *(const float4*)(x + i + 4);
    short8 s;
    s[0]=(short)f2b(a.x); s[1]=(short)f2b(a.y); s[2]=(short)f2b(a.z); s[3]=(short)f2b(a.w);
    s[4]=(short)f2b(b.x); s[5]=(short)f2b(b.y); s[6]=(short)f2b(b.z); s[7]=(short)f2b(b.w);
    *(short8*)(xb + i) = s;
    return;
  }
  const float* in; unsigned short* out; int R, C, bx, by;
  if (bid < 2240){ int t = bid - 2048; bx = t % 24; by = t / 24; in = Wqkv; out = wqkvT; R = 512; C = 1536; }
  else           { int t = bid - 2240; bx = t % 8;  by = t / 8;  in = Wproj; out = wprojT; R = 512; C = 512; }
  const int r0 = by * 64, c0 = bx * 64;
  {
    const int i = tid >> 2, jg = (tid & 3) * 16;
    const float* src = in + (size_t)(r0 + i) * C + c0 + jg;
    #pragma unroll
    for (int e = 0; e < 16; e += 4){
      float4 v = *(const float4*)(src + e);
      T[i][jg + e + 0] = f2b(v.x);
      T[i][jg + e + 1] = f2b(v.y);
      T[i][jg + e + 2] = f2b(v.z);
      T[i][jg + e + 3] = f2b(v.w);
    }
  }
  __syncthreads();
  {
    const int j = tid >> 2, ig = (tid & 3) * 16;
    short8 w0, w1;
    #pragma unroll
    for (int e = 0; e < 8; e++) w0[e] = (short)T[ig + e][j];
    #pragma unroll
    for (int e = 0; e < 8; e++) w1[e] = (short)T[ig + 8 + e][j];
    unsigned short* dst = out + (size_t)(c0 + j) * R + r0 + ig;
    *(short8*)dst = w0;
    *(short8*)(dst + 8) = w1;
  }
}

// ---------------- QKV GEMM (BK=64, global_load_lds, XCD-swizzled, 3 blocks/CU) ----------------
__global__ __launch_bounds__(256,3) void gemm_qkv_kernel(
    const unsigned short* __restrict__ A,
    const unsigned short* __restrict__ Bt,
    const float* __restrict__ bias,
    unsigned short* __restrict__ Qb,
    unsigned short* __restrict__ Kb,
    unsigned short* __restrict__ VTb,
    float* __restrict__ Mq, float* __restrict__ Mk){
  __shared__ unsigned short As[128*64];
  __shared__ unsigned short Bs[128*64];
  const int tid = threadIdx.x, wid = tid >> 6, lane = tid & 63;
  const int wr = wid >> 1, wc = wid & 1;
  const int fr = lane & 15, fq = lane >> 4;
  const int fr7 = fr & 7;
  const int orig = blockIdx.x;
  const int xcd = orig & 7, idx = orig >> 3;
  const int bm = (xcd + 8*(idx/12)) * 128;
  const int bn = (idx % 12) * 128;
  f32x4 acc[4][4];
  #pragma unroll
  for (int m=0;m<4;m++)
    #pragma unroll
    for (int n=0;n<4;n++) acc[m][n] = (f32x4){0.f,0.f,0.f,0.f};

  for (int k0 = 0; k0 < 512; k0 += 64){
    __syncthreads();
    #pragma unroll
    for (int it=0; it<4; it++){
      const int s = it*256 + tid;
      const int row = s >> 3, c = s & 7;
      const int sc = c ^ (row & 7);
      void* al = (void*)(As + (it*256 + wid*64)*8);
      void* bl = (void*)(Bs + (it*256 + wid*64)*8);
      gload16(A  + (size_t)(bm + row)*512 + k0 + sc*8, al);
      gload16(Bt + (size_t)(bn + row)*512 + k0 + sc*8, bl);
    }
    __syncthreads();
    bf16x8 af[4][2], bfv[4][2];
    #pragma unroll
    for (int m=0;m<4;m++)
      #pragma unroll
      for (int kk=0;kk<2;kk++)
        af[m][kk]  = *(const bf16x8*)&As[(wr*64 + m*16 + fr)*64 + (((kk*4+fq)^fr7)*8)];
    #pragma unroll
    for (int n=0;n<4;n++)
      #pragma unroll
      for (int kk=0;kk<2;kk++)
        bfv[n][kk] = *(const bf16x8*)&Bs[(wc*64 + n*16 + fr)*64 + (((kk*4+fq)^fr7)*8)];
    #pragma unroll
    for (int kk=0;kk<2;kk++)
      #pragma unroll
      for (int m=0;m<4;m++)
        #pragma unroll
        for (int n=0;n<4;n++)
          acc[m][n] = __builtin_amdgcn_mfma_f32_16x16x32_bf16(af[m][kk], bfv[n][kk], acc[m][n], 0,0,0);
  }

  const float SCQ = 0.125f * LOG2E;
  const int colbase = bn + wc*64;
  const int which = colbase >> 9;
  float ss[4][4];
  #pragma unroll
  for (int m=0;m<4;m++)
    #pragma unroll
    for (int g=0;g<4;g++) ss[m][g] = 0.f;

  #pragma unroll
  for (int m=0;m<4;m++){
    const int row0 = bm + wr*64 + m*16 + fq*4;
    const int b_ = row0 >> 11, t_ = row0 & 2047;
    #pragma unroll
    for (int n=0;n<4;n++){
      const int col = colbase + n*16 + fr;
      const int c = col & 511, hh = c >> 6, dd = c & 63;
      const float bv = bias[col];
      if (which == 0){
        #pragma unroll
        for (int g=0; g<4; g++){
          const float v = (acc[m][n][g] + bv) * SCQ;
          ss[m][g] = fmaf(v, v, ss[m][g]);
          Qb[((size_t)(b_*8 + hh)*2048 + t_ + g)*64 + dd] = f2b(v);
        }
      } else if (which == 1){
        #pragma unroll
        for (int g=0; g<4; g++){
          const float v = acc[m][n][g] + bv;
          ss[m][g] = fmaf(v, v, ss[m][g]);
          Kb[((size_t)(b_*8 + hh)*2048 + t_ + g)*64 + dd] = f2b(v);
        }
      } else {
        uint2 pk;
        pk.x = cvtpk(acc[m][n][0] + bv, acc[m][n][1] + bv);
        pk.y = cvtpk(acc[m][n][2] + bv, acc[m][n][3] + bv);
        *(uint2*)&VTb[((size_t)(b_*8 + hh)*64 + dd)*2048 + t_] = pk;
      }
    }
  }

  if (which <= 1){
    #pragma unroll
    for (int m=0;m<4;m++)
      #pragma unroll
      for (int g=0;g<4;g++){
        float s = ss[m][g];
        s += __shfl_xor(s, 1); s += __shfl_xor(s, 2);
        s += __shfl_xor(s, 4); s += __shfl_xor(s, 8);
        ss[m][g] = s;
      }
    float mx = 0.f;
    #pragma unroll
    for (int m=0;m<4;m++)
      #pragma unroll
      for (int g=0;g<4;g++) mx = fmaxf(mx, ss[m][g]);
    mx = fmaxf(mx, __shfl_xor(mx, 16));
    mx = fmaxf(mx, __shfl_xor(mx, 32));
    if (lane == 0){
      const int rowbase = bm + wr*64;
      const int b_ = rowbase >> 11, qc_ = (rowbase >> 6) & 31;
      const int h_ = (colbase >> 6) & 7;
      float* M = which ? Mk : Mq;
      M[(b_*8 + h_)*32 + qc_] = sqrtf(mx) * 1.01f;
    }
  }
}

// ---------------- windowed flash attention, static-shift softmax ----------------
__global__ __launch_bounds__(256,3) void attn_kernel(
    const unsigned short* __restrict__ Q,
    const unsigned short* __restrict__ K,
    const unsigned short* __restrict__ VT,
    const float* __restrict__ alib,
    const float* __restrict__ Mqa,
    const float* __restrict__ Mka,
    unsigned short* __restrict__ Y){
  __shared__ unsigned short Ks[2][64*64];
  __shared__ unsigned short Vs[2][64*64];
  __shared__ unsigned short Ps[4][16][72];
  __shared__ float MkS[32];
  __shared__ float wred[4];
  __shared__ int lst[32];
  __shared__ int nsh;
  const int tid = threadIdx.x, wid = tid >> 6, lane = tid & 63;
  const int fr = lane & 15, fq = lane >> 4;
  const int fr7 = fr & 7;
  const int id = blockIdx.x;
  const int h = id >> 7;
  const int low3 = id & 7, idx4 = (id & 127) >> 3;
  const int b = idx4 >> 2, off = idx4 & 3;
  const int quad = (low3 - b) & 7;
  const int qc = quad*4 + off;
  const int bh = b*8 + h;
  const int q0 = qc*64 + wid*16;
  const unsigned short* Qp = Q  + (size_t)bh * 131072;
  const unsigned short* Kp = K  + (size_t)bh * 131072;
  const unsigned short* Vp = VT + (size_t)bh * 131072;
  const float nmh2 = alib[(size_t)h * 4194304 + 1] * LOG2E;
  const float MqMk0 = Mqa[bh*32 + qc];
  if (tid < 32) MkS[tid] = Mka[bh*32 + tid];

  float vmk = Mka[bh*32 + (lane & 31)];
  #pragma unroll
  for (int d=1; d<32; d<<=1) vmk = fmaxf(vmk, __shfl_xor(vmk, d));
  const float msta = MqMk0 * vmk;

  bf16x8 qf[2];
  #pragma unroll
  for (int kk=0;kk<2;kk++)
    qf[kk] = *(const bf16x8*)(Qp + (size_t)(q0 + fr)*64 + kk*32 + fq*8);

  bf16x8 ones;
  #pragma unroll
  for (int e=0;e<8;e++) ones[e] = __builtin_bit_cast(__bf16, (unsigned short)0x3F80);

  f32x4 o[4], osum;
  #pragma unroll
  for (int ni=0;ni<4;ni++) o[ni] = (f32x4){0.f,0.f,0.f,0.f};
  osum = (f32x4){0.f,0.f,0.f,0.f};
  float rowmax = -1e30f;
  const float qi = (float)(q0 + fr);
  const float qb = nmh2 * qi;
  f32x4 ka[4];
  #pragma unroll
  for (int ni=0;ni<4;ni++)
    #pragma unroll
    for (int g=0;g<4;g++) ka[ni][g] = nmh2 * (float)(ni*16 + fq*4 + g);

  auto stage = [&](int kt, int buf){
    const int kb = kt * 64;
    #pragma unroll
    for (int it=0; it<2; it++){
      const int s = it*256 + tid;
      const int row = s >> 3, c = s & 7;
      const int sc = c ^ (row & 7);
      gload16(Kp + (size_t)(kb + row)*64 + sc*8, (void*)(Ks[buf] + (it*256 + wid*64)*8));
      gload16(Vp + (size_t)row*2048 + kb + sc*8, (void*)(Vs[buf] + (it*256 + wid*64)*8));
    }
  };

  auto compute = [&](int kt, int buf, bool diag){
    const int kb = kt * 64;
    const unsigned short* KsB = Ks[buf];
    const unsigned short* VsB = Vs[buf];
    bf16x8 kf[4][2], vf[4][2];
    #pragma unroll
    for (int ni=0;ni<4;ni++)
      #pragma unroll
      for (int kk=0;kk<2;kk++){
        const int r = ni*16 + fr;
        const int sw = ((kk*4 + fq) ^ fr7) * 8;
        kf[ni][kk] = *(const bf16x8*)&KsB[r*64 + sw];
        vf[ni][kk] = *(const bf16x8*)&VsB[r*64 + sw];
      }

    f32x4 st[4];
    const f32x4 fz = {0.f,0.f,0.f,0.f};
    #pragma unroll
    for (int ni=0;ni<4;ni++){
      f32x4 t0 = __builtin_amdgcn_mfma_f32_16x16x32_bf16(kf[ni][0], qf[0], fz, 0,0,0);
      st[ni] = __builtin_amdgcn_mfma_f32_16x16x32_bf16(kf[ni][1], qf[1], t0, 0,0,0);
    }

    float cadd;
    if (diag){
      const float base = qi - (float)(kb + fq*4);
      #pragma unroll
      for (int ni=0;ni<4;ni++)
        #pragma unroll
        for (int g=0;g<4;g++){
          const float d = fabsf(base - (float)(ni*16 + g));
          st[ni][g] = fmaf(nmh2, d, st[ni][g]);
        }
      cadd = 0.f;
      float m0 = fmaxf(fmaxf(st[0][0], st[0][1]), fmaxf(st[0][2], st[0][3]));
      float m1 = fmaxf(fmaxf(st[1][0], st[1][1]), fmaxf(st[1][2], st[1][3]));
      float m2 = fmaxf(fmaxf(st[2][0], st[2][1]), fmaxf(st[2][2], st[2][3]));
      float m3 = fmaxf(fmaxf(st[3][0], st[3][1]), fmaxf(st[3][2], st[3][3]));
      float tm = fmaxf(fmaxf(m0, m1), fmaxf(m2, m3));
      tm = fmaxf(tm, __shfl_xor(tm, 16));
      tm = fmaxf(tm, __shfl_xor(tm, 32));
      rowmax = tm;
    } else {
      const float s1 = (kt > qc) ? 1.f : -1.f;
      #pragma unroll
      for (int ni=0;ni<4;ni++)
        #pragma unroll
        for (int g=0;g<4;g++)
          st[ni][g] = fmaf(s1, ka[ni][g], st[ni][g]);
      cadd = s1 * (nmh2 * (float)kb - qb);
    }

    const float mexp = msta - cadd;
    #pragma unroll
    for (int ni=0;ni<4;ni++)
      #pragma unroll
      for (int g=0;g<4;g++)
        st[ni][g] = exp2f(st[ni][g] - mexp);

    #pragma unroll
    for (int ni=0;ni<4;ni++){
      uint2 pk;
      pk.x = cvtpk(st[ni][0], st[ni][1]);
      pk.y = cvtpk(st[ni][2], st[ni][3]);
      *(uint2*)&Ps[wid][fr][ni*16 + fq*4] = pk;
    }

    bf16x8 pf[2];
    #pragma unroll
    for (int kk=0;kk<2;kk++)
      pf[kk] = *(const bf16x8*)&Ps[wid][fr][kk*32 + fq*8];
    #pragma unroll
    for (int ni=0;ni<4;ni++){
      o[ni] = __builtin_amdgcn_mfma_f32_16x16x32_bf16(pf[0], vf[ni][0], o[ni], 0,0,0);
      o[ni] = __builtin_amdgcn_mfma_f32_16x16x32_bf16(pf[1], vf[ni][1], o[ni], 0,0,0);
    }
    osum = __builtin_amdgcn_mfma_f32_16x16x32_bf16(pf[0], ones, osum, 0,0,0);
    osum = __builtin_amdgcn_mfma_f32_16x16x32_bf16(pf[1], ones, osum, 0,0,0);
  };

  // ---- prologue: stage diag + first ring tile together, overlap ----
  const int e0 = (qc + 1 < 32) ? qc + 1 : qc - 1;
  const int e1 = (qc + 1 < 32 && qc - 1 >= 0) ? qc - 1 : -1;
  stage(qc, 0);
  stage(e0, 1);
  asm volatile("s_waitcnt vmcnt(4)" ::: "memory");
  __builtin_amdgcn_sched_barrier(0);
  __builtin_amdgcn_s_barrier();
  compute(qc, 0, true);

  // ---- thresholds (block + per-wave, from diag row maxes) ----
  float wm = rowmax;
  #pragma unroll
  for (int d=1; d<16; d<<=1) wm = fminf(wm, __shfl_xor(wm, d));
  if (lane == 0) wred[wid] = wm;
  __syncthreads();
  const float thresh  = fminf(fminf(wred[0], wred[1]), fminf(wred[2], wred[3])) - 14.0f;
  const float threshW = wm - 14.0f;

  // ---- build tile list: e1 first, then dt>=2 ----
  if (tid == 0){
    float maxMk = 0.f;
    #pragma unroll
    for (int t=0; t<32; t++) maxMk = fmaxf(maxMk, MkS[t]);
    int n = 0;
    if (e1 >= 0) lst[n++] = e1;
    for (int dt = 2; dt < 32; dt++){
      const float biasmax = nmh2 * (float)((dt - 1)*64 + 1);
      if (MqMk0 * maxMk + biasmax < thresh) break;
      int kt = qc + dt;
      if (kt < 32 && MqMk0 * MkS[kt] + biasmax >= thresh) lst[n++] = kt;
      kt = qc - dt;
      if (kt >= 0 && MqMk0 * MkS[kt] + biasmax >= thresh) lst[n++] = kt;
    }
    nsh = n;
  }
  __syncthreads();
  const int nt = nsh + 1;

  // ---- pipelined loop: tile j lives in buffer (j+1)&1 ----
  for (int j = 0; j < nt; j++){
    const int kt = (j == 0) ? e0 : lst[j-1];
    asm volatile("s_waitcnt lgkmcnt(0)" ::: "memory");
    __builtin_amdgcn_sched_barrier(0);
    __builtin_amdgcn_s_barrier();
    if (j + 1 < nt){
      stage((j == 0) ? lst[0] : lst[j], j & 1);
      asm volatile("s_waitcnt vmcnt(4)" ::: "memory");
    } else {
      asm volatile("s_waitcnt vmcnt(0)" ::: "memory");
    }
    __builtin_amdgcn_sched_barrier(0);
    __builtin_amdgcn_s_barrier();
    const int dminW = (kt > qc) ? (kt*64 - (q0 + 15)) : (q0 - (kt*64 + 63));
    if (MqMk0 * MkS[kt] + nmh2 * (float)dminW >= threshW)
      compute(kt, (j+1)&1, false);
  }

  // ---- epilogue ----
  #pragma unroll
  for (int g=0;g<4;g++){
    const float iv = 1.0f / osum[g];
    const int t = q0 + fq*4 + g;
    #pragma unroll
    for (int ni=0;ni<4;ni++)
      Y[(size_t)(b*2048 + t)*512 + h*64 + ni*16 + fr] = f2b(o[ni][g] * iv);
  }
}

// ---------------- output projection GEMM (BK=64, global_load_lds, XCD-swizzled) ----------------
__global__ __launch_bounds__(256,2) void gemm_proj_kernel(
    const unsigned short* __restrict__ A,
    const unsigned short* __restrict__ Bt,
    const float* __restrict__ bias,
    float* __restrict__ out){
  __shared__ unsigned short As[128*64];
  __shared__ unsigned short Bs[128*64];
  const int tid = threadIdx.x, wid = tid >> 6, lane = tid & 63;
  const int wr = wid >> 1, wc = wid & 1;
  const int fr = lane & 15, fq = lane >> 4;
  const int fr7 = fr & 7;
  const int orig = blockIdx.x;
  const int xcd = orig & 7, idx = orig >> 3;
  const int bm = (xcd + 8*(idx >> 2)) * 128;
  const int bn = (idx & 3) * 128;
  f32x4 acc[4][4];
  #pragma unroll
  for (int m=0;m<4;m++)
    #pragma unroll
    for (int n=0;n<4;n++) acc[m][n] = (f32x4){0.f,0.f,0.f,0.f};

  for (int k0 = 0; k0 < 512; k0 += 64){
    __syncthreads();
    #pragma unroll
    for (int it=0; it<4; it++){
      const int s = it*256 + tid;
      const int row = s >> 3, c = s & 7;
      const int sc = c ^ (row & 7);
      void* al = (void*)(As + (it*256 + wid*64)*8);
      void* bl = (void*)(Bs + (it*256 + wid*64)*8);
      gload16(A  + (size_t)(bm + row)*512 + k0 + sc*8, al);
      gload16(Bt + (size_t)(bn + row)*512 + k0 + sc*8, bl);
    }
    __syncthreads();
    bf16x8 af[4][2], bfv[4][2];
    #pragma unroll
    for (int m=0;m<4;m++)
      #pragma unroll
      for (int kk=0;kk<2;kk++)
        af[m][kk]  = *(const bf16x8*)&As[(wr*64 + m*16 + fr)*64 + (((kk*4+fq)^fr7)*8)];
    #pragma unroll
    for (int n=0;n<4;n++)
      #pragma unroll
      for (int kk=0;kk<2;kk++)
        bfv[n][kk] = *(const bf16x8*)&Bs[(wc*64 + n*16 + fr)*64 + (((kk*4+fq)^fr7)*8)];
    #pragma unroll
    for (int kk=0;kk<2;kk++)
      #pragma unroll
      for (int m=0;m<4;m++)
        #pragma unroll
        for (int n=0;n<4;n++)
          acc[m][n] = __builtin_amdgcn_mfma_f32_16x16x32_bf16(af[m][kk], bfv[n][kk], acc[m][n], 0,0,0);
  }

  #pragma unroll
  for (int m=0;m<4;m++){
    const int row0 = bm + wr*64 + m*16 + fq*4;
    #pragma unroll
    for (int n=0;n<4;n++){
      const int col = bn + wc*64 + n*16 + fr;
      const float bv = bias[col];
      #pragma unroll
      for (int g=0; g<4; g++)
        out[(size_t)(row0 + g)*512 + col] = acc[m][n][g] + bv;
    }
  }
}

// ---------------- launch ----------------
extern "C" void kernel_launch(void* const* d_in, const int* in_sizes, int n_in,
                              void* d_out, int out_size, void* d_ws, size_t ws_size,
                              hipStream_t stream){
  const float* x     = (const float*)d_in[0];
  const float* Wqkv  = (const float*)d_in[1];
  const float* bqkv  = (const float*)d_in[2];
  const float* Wproj = (const float*)d_in[3];
  const float* bproj = (const float*)d_in[4];
  const float* alib  = (const float*)d_in[5];
  char* ws = (char*)d_ws;
  unsigned short* xb     = (unsigned short*)(ws);
  unsigned short* wqkvT  = (unsigned short*)(ws + 8388608);
  unsigned short* wprojT = (unsigned short*)(ws + 9961472);
  unsigned short* Qb     = (unsigned short*)(ws + 10485760);
  unsigned short* Kb     = (unsigned short*)(ws + 18874368);
  unsigned short* VTb    = (unsigned short*)(ws + 27262976);
  unsigned short* Yb     = (unsigned short*)(ws + 35651584);
  float* out = (float*)d_out;
  float* Mq = out + 4194304 - 2048;
  float* Mk = Mq + 1024;

  prep_kernel<<<2304, 256, 0, stream>>>(x, Wqkv, Wproj, xb, wqkvT, wprojT);
  gemm_qkv_kernel<<<768, 256, 0, stream>>>(xb, wqkvT, bqkv, Qb, Kb, VTb, Mq, Mk);
  attn_kernel<<<1024, 256, 0, stream>>>(Qb, Kb, VTb, alib, Mq, Mk, Yb);
  gemm_proj_kernel<<<256, 256, 0, stream>>>(Yb, wprojT, bproj, out);
}